// Round 1
// 370.382 us; speedup vs baseline: 1.0283x; 1.0283x over previous
//
#include <hip/hip_runtime.h>

// Problem constants (fixed by the reference)
#define NN 32768      // nodes
#define EE 262144     // edges
#define DM 512        // input/model dim (K of the big GEMM)
#define NQKV 1536     // q|k|v concatenated
#define NHEAD 8
#define DHEAD 64

typedef unsigned short u16;
typedef unsigned int u32;
typedef __attribute__((ext_vector_type(8))) short bf16x8;   // MFMA A/B operand (8 bf16)
typedef __attribute__((ext_vector_type(4))) float f32x4;    // MFMA C/D
typedef __attribute__((ext_vector_type(8))) u16 u16x8;
typedef __attribute__((ext_vector_type(4))) u32 u32x4;

__device__ __forceinline__ float bf2f(u16 u) {
  union { u32 i; float f; } x; x.i = ((u32)u) << 16; return x.f;
}
__device__ __forceinline__ float bflo(u32 p) {
  union { u32 i; float f; } x; x.i = p << 16; return x.f;
}
__device__ __forceinline__ float bfhi(u32 p) {
  union { u32 i; float f; } x; x.i = p & 0xFFFF0000u; return x.f;
}
__device__ __forceinline__ u16 f2bf(float f) {
  union { float f; u32 i; } x; x.f = f;
  u32 r = x.i + 0x7FFFu + ((x.i >> 16) & 1u);   // RNE
  return (u16)(r >> 16);
}

__device__ __forceinline__ void load_lds16(const u16* g, u16* l) {
  __builtin_amdgcn_global_load_lds(
      (const __attribute__((address_space(1))) char*)(const void*)g,
      (__attribute__((address_space(3))) char*)(void*)l, 16, 0, 0);
}

// XOR chunk swizzle for the 4x16B chunks of a 32-elem LDS row: spreads the
// fragment ds_read_b128 bank pattern from 8-way to ~2-way (free, m136).
// Involution in s for fixed r, so staging and reading use the same formula.
__device__ __forceinline__ int swz(int r, int s) {
  return s ^ (r & 3) ^ ((r >> 2) & 1);
}

// Output column permutation: q_j -> j; k_d -> 512+2d; v_d -> 513+2d.
// GEMM columns then directly produce the unified qkv row layout
// [q(512) | kv-interleaved(1024)], making the epilogue a contiguous store.

// ---------------------------------------------------------------------------
// Transpose-cast Wq/Wk/Wv -> At[perm(z,j)][m] = Wsel[m][j] * scale  (bf16)
// ---------------------------------------------------------------------------
__global__ void tcast_w(const float* __restrict__ Wq, const float* __restrict__ Wk,
                        const float* __restrict__ Wv, u16* __restrict__ At) {
  const int z = blockIdx.z;           // 0=q,1=k,2=v
  const float* W = (z == 0) ? Wq : (z == 1) ? Wk : Wv;
  const float scale = (z == 0) ? 0.125f : 1.0f;
  const int m0 = blockIdx.x * 64;     // source row block (m)
  const int j0 = blockIdx.y * 64;     // source col block (j)
  __shared__ float t[64][65];
  const int tx = threadIdx.x & 63, ty = threadIdx.x >> 6;
#pragma unroll
  for (int i = 0; i < 16; ++i) {
    const int r = ty * 16 + i;
    t[r][tx] = W[(size_t)(m0 + r) * 512 + (j0 + tx)];   // coalesced over tx
  }
  __syncthreads();
#pragma unroll
  for (int i = 0; i < 16; ++i) {
    const int j = j0 + ty * 16 + i;
    const int pr = (z == 0) ? j : (512 + 2 * j + (z - 1));  // permuted row
    At[(size_t)pr * 512 + (m0 + tx)] = f2bf(t[tx][ty * 16 + i] * scale);
  }
}

// Win fp32 -> bf16 (already [kk][m] = B^T layout for the compose GEMM)
__global__ void cast_win(const float* __restrict__ Win, u16* __restrict__ Winb) {
  const int i = (blockIdx.x * 256 + threadIdx.x) * 8;
  float4 a = *(const float4*)&Win[i];
  float4 b = *(const float4*)&Win[i + 4];
  u16x8 o = { f2bf(a.x), f2bf(a.y), f2bf(a.z), f2bf(a.w),
              f2bf(b.x), f2bf(b.y), f2bf(b.z), f2bf(b.w) };
  *(u16x8*)&Winb[i] = o;
}

__global__ void make_bias(const float* __restrict__ bin,
                          const float* __restrict__ Wq, const float* __restrict__ bq,
                          const float* __restrict__ Wk, const float* __restrict__ bk,
                          const float* __restrict__ Wv, const float* __restrict__ bv,
                          float* __restrict__ bias) {
  const int j = blockIdx.x * 256 + threadIdx.x;   // logical index
  if (j >= 1536) return;
  const float* Wsel; const float* bsel; int jj; float scale = 1.0f; int pos;
  if (j < 512)       { Wsel = Wq; bsel = bq; jj = j;        scale = 0.125f; pos = j; }
  else if (j < 1024) { Wsel = Wk; bsel = bk; jj = j - 512;  pos = 512 + 2 * jj; }
  else               { Wsel = Wv; bsel = bv; jj = j - 1024; pos = 513 + 2 * jj; }
  float s = 0.f;
  for (int m = 0; m < 512; ++m) s = fmaf(bin[m], Wsel[m * 512 + jj], s);
  bias[pos] = (s + bsel[jj]) * scale;
}

// h fp32 -> bf16 (GEMM A operand)
__global__ void cast_h(const float* __restrict__ h, u16* __restrict__ hb) {
  const int i = (blockIdx.x * 256 + threadIdx.x) * 8;
  float4 a = *(const float4*)&h[i];
  float4 b = *(const float4*)&h[i + 4];
  u16x8 o = { f2bf(a.x), f2bf(a.y), f2bf(a.z), f2bf(a.w),
              f2bf(b.x), f2bf(b.y), f2bf(b.z), f2bf(b.w) };
  *(u16x8*)&hb[i] = o;
}

// ---------------------------------------------------------------------------
// CSR build on `row`
// ---------------------------------------------------------------------------
__global__ void count_deg(const int* __restrict__ row, int* __restrict__ deg) {
  const int e = blockIdx.x * 256 + threadIdx.x;
  atomicAdd(&deg[row[e]], 1);
}

__global__ void scan_deg(const int* __restrict__ deg, int* __restrict__ row_ptr,
                         int* __restrict__ cursor) {
  __shared__ int sums[1024];
  const int t = threadIdx.x;
  const int base = t * 32;
  int loc[32];
  int s = 0;
#pragma unroll
  for (int i = 0; i < 32; ++i) { loc[i] = s; s += deg[base + i]; }
  sums[t] = s;
  __syncthreads();
  for (int off = 1; off < 1024; off <<= 1) {
    int v = (t >= off) ? sums[t - off] : 0;
    __syncthreads();
    sums[t] += v;
    __syncthreads();
  }
  const int excl = sums[t] - s;
#pragma unroll
  for (int i = 0; i < 32; ++i) {
    const int val = excl + loc[i];
    row_ptr[base + i] = val;
    cursor[base + i] = val;
  }
  if (t == 1023) row_ptr[NN] = sums[1023];
}

__global__ void fill_csr(const int* __restrict__ row, const int* __restrict__ col,
                         int* __restrict__ cursor, int* __restrict__ dst) {
  const int e = blockIdx.x * 256 + threadIdx.x;
  const int r = row[e];
  const int p = atomicAdd(&cursor[r], 1);
  dst[p] = col[e];
}

// ---------------------------------------------------------------------------
// Compose GEMM: Wt[j][kk] = sum_m At[j][m] * Winb[kk][m]
// M=1536, N=512, K=512. m97 structure + chunk swizzle + 2-phase pipeline.
// 48 blocks (~1/CU): no inter-block latency hiding, so the software pipeline
// (stage t+1 before compute t) is what covers the global->LDS latency.
// ---------------------------------------------------------------------------
__global__ __launch_bounds__(256, 2) void gemm_wt(
    const u16* __restrict__ A,    // At [1536][512] bf16 (rows pre-permuted)
    const u16* __restrict__ B,    // Winb [512][512] bf16 (B^T layout)
    u16* __restrict__ C) {        // Wt [1536][512] bf16
  __shared__ u16 As[2][128 * 32];
  __shared__ u16 Bs[2][128 * 32];
  const int tid = threadIdx.x;
  const int lane = tid & 63;
  const int wave = tid >> 6;
  const int quad = lane >> 4;
  const int l16 = lane & 15;
  const int m0 = blockIdx.y * 128;
  const int n0 = blockIdx.x * 128;
  const int wm = (wave >> 1) * 64;
  const int wn = (wave & 1) * 64;

  const int c0 = tid, c1 = tid + 256;
  const int r0 = c0 >> 2, ko0 = swz(r0, c0 & 3) * 8;
  const int r1 = c1 >> 2, ko1 = swz(r1, c1 & 3) * 8;
  const u16* Ag0 = A + (size_t)(m0 + r0) * DM + ko0;
  const u16* Ag1 = A + (size_t)(m0 + r1) * DM + ko1;
  const u16* Bg0 = B + (size_t)(n0 + r0) * DM + ko0;
  const u16* Bg1 = B + (size_t)(n0 + r1) * DM + ko1;

  f32x4 acc[4][4];
#pragma unroll
  for (int i = 0; i < 4; ++i)
#pragma unroll
    for (int j = 0; j < 4; ++j) acc[i][j] = (f32x4){0.f, 0.f, 0.f, 0.f};

  // prologue: stage k-tile 0 into buffer 0
  load_lds16(Ag0, &As[0][c0 * 8]);
  load_lds16(Bg0, &Bs[0][c0 * 8]);
  load_lds16(Ag1, &As[0][c1 * 8]);
  load_lds16(Bg1, &Bs[0][c1 * 8]);
  __syncthreads();

  int cur = 0;
#pragma unroll
  for (int kt = 32; kt < DM; kt += 32) {
    // stage NEXT k-tile into the other buffer (latency hidden under compute)
    load_lds16(Ag0 + kt, &As[cur ^ 1][c0 * 8]);
    load_lds16(Bg0 + kt, &Bs[cur ^ 1][c0 * 8]);
    load_lds16(Ag1 + kt, &As[cur ^ 1][c1 * 8]);
    load_lds16(Bg1 + kt, &Bs[cur ^ 1][c1 * 8]);
    // compute CURRENT k-tile
    bf16x8 a[4], b[4];
#pragma unroll
    for (int i = 0; i < 4; ++i) {
      const int ra = wm + i * 16 + l16;
      const int rb = wn + i * 16 + l16;
      a[i] = *(const bf16x8*)&As[cur][ra * 32 + swz(ra, quad) * 8];
      b[i] = *(const bf16x8*)&Bs[cur][rb * 32 + swz(rb, quad) * 8];
    }
#pragma unroll
    for (int mi = 0; mi < 4; ++mi)
#pragma unroll
      for (int ni = 0; ni < 4; ++ni)
        acc[mi][ni] = __builtin_amdgcn_mfma_f32_16x16x32_bf16(a[mi], b[ni], acc[mi][ni], 0, 0, 0);
    __syncthreads();   // drains vmcnt: next buffer is ready
    cur ^= 1;
  }
  { // last k-tile
    bf16x8 a[4], b[4];
#pragma unroll
    for (int i = 0; i < 4; ++i) {
      const int ra = wm + i * 16 + l16;
      const int rb = wn + i * 16 + l16;
      a[i] = *(const bf16x8*)&As[cur][ra * 32 + swz(ra, quad) * 8];
      b[i] = *(const bf16x8*)&Bs[cur][rb * 32 + swz(rb, quad) * 8];
    }
#pragma unroll
    for (int mi = 0; mi < 4; ++mi)
#pragma unroll
      for (int ni = 0; ni < 4; ++ni)
        acc[mi][ni] = __builtin_amdgcn_mfma_f32_16x16x32_bf16(a[mi], b[ni], acc[mi][ni], 0, 0, 0);
  }

#pragma unroll
  for (int ni = 0; ni < 4; ++ni) {
    const int coln = n0 + wn + ni * 16 + l16;
#pragma unroll
    for (int mi = 0; mi < 4; ++mi) {
#pragma unroll
      for (int r = 0; r < 4; ++r) {
        const int rowm = m0 + wm + mi * 16 + quad * 4 + r;
        C[(size_t)rowm * 512 + coln] = f2bf(acc[mi][ni][r]);
      }
    }
  }
}

// ---------------------------------------------------------------------------
// QKV = h_bf16 @ Wt^T + bias   (M=32768, N=1536, K=512)
// B rows are pre-permuted so output columns ARE the unified qkv layout.
// 2-phase double-buffered pipeline (T3 minimum recipe) + XCD-aware swizzle
// (T1): nwg=3072 = 8*384, so XCD x gets by in [32x,32x+32) for all bx ->
// each A row-panel fetched from HBM once, then L2-resident for its 12
// consumers; B (1.5 MB) L2-resident per XCD.
// ---------------------------------------------------------------------------
__global__ __launch_bounds__(256, 2) void gemm_qkv(
    const u16* __restrict__ A,    // [32768,512] bf16, row-major
    const u16* __restrict__ B,    // [1536,512] bf16, N-major, rows permuted
    const float* __restrict__ bias,  // permuted to match columns
    u16* __restrict__ C) {        // qkv [32768,1536] bf16 unified
  __shared__ u16 As[2][128 * 32];
  __shared__ u16 Bs[2][128 * 32];
  const int tid = threadIdx.x;
  const int lane = tid & 63;
  const int wave = tid >> 6;
  const int quad = lane >> 4;
  const int l16 = lane & 15;

  // XCD swizzle: bid%8 is the (assumed round-robin) XCD; give each XCD a
  // contiguous chunk of tile space. 3072 % 8 == 0 -> bijective.
  const int bid = blockIdx.y * 12 + blockIdx.x;
  const int sw = (bid & 7) * 384 + (bid >> 3);
  const int bx = sw % 12;
  const int by = sw / 12;
  const int m0 = by * 128;
  const int n0 = bx * 128;
  const int wm = (wave >> 1) * 64;
  const int wn = (wave & 1) * 64;

  const int c0 = tid, c1 = tid + 256;
  const int r0 = c0 >> 2, ko0 = swz(r0, c0 & 3) * 8;
  const int r1 = c1 >> 2, ko1 = swz(r1, c1 & 3) * 8;
  const u16* Ag0 = A + (size_t)(m0 + r0) * DM + ko0;
  const u16* Ag1 = A + (size_t)(m0 + r1) * DM + ko1;
  const u16* Bg0 = B + (size_t)(n0 + r0) * DM + ko0;
  const u16* Bg1 = B + (size_t)(n0 + r1) * DM + ko1;

  f32x4 acc[4][4];
#pragma unroll
  for (int i = 0; i < 4; ++i)
#pragma unroll
    for (int j = 0; j < 4; ++j) acc[i][j] = (f32x4){0.f, 0.f, 0.f, 0.f};

  // prologue: stage k-tile 0 into buffer 0
  load_lds16(Ag0, &As[0][c0 * 8]);
  load_lds16(Bg0, &Bs[0][c0 * 8]);
  load_lds16(Ag1, &As[0][c1 * 8]);
  load_lds16(Bg1, &Bs[0][c1 * 8]);
  __syncthreads();

  int cur = 0;
#pragma unroll
  for (int kt = 32; kt < DM; kt += 32) {
    // stage NEXT k-tile (async global->LDS, drains at the barrier below,
    // latency hidden under this tile's ds_read + 16 MFMAs)
    load_lds16(Ag0 + kt, &As[cur ^ 1][c0 * 8]);
    load_lds16(Bg0 + kt, &Bs[cur ^ 1][c0 * 8]);
    load_lds16(Ag1 + kt, &As[cur ^ 1][c1 * 8]);
    load_lds16(Bg1 + kt, &Bs[cur ^ 1][c1 * 8]);
    // compute CURRENT k-tile
    bf16x8 a[4], b[4];
#pragma unroll
    for (int i = 0; i < 4; ++i) {
      const int ra = wm + i * 16 + l16;
      const int rb = wn + i * 16 + l16;
      a[i] = *(const bf16x8*)&As[cur][ra * 32 + swz(ra, quad) * 8];
      b[i] = *(const bf16x8*)&Bs[cur][rb * 32 + swz(rb, quad) * 8];
    }
#pragma unroll
    for (int mi = 0; mi < 4; ++mi)
#pragma unroll
      for (int ni = 0; ni < 4; ++ni)
        acc[mi][ni] = __builtin_amdgcn_mfma_f32_16x16x32_bf16(a[mi], b[ni], acc[mi][ni], 0, 0, 0);
    __syncthreads();   // single barrier per k-step; vmcnt(0) makes next buffer ready
    cur ^= 1;
  }
  { // last k-tile (already staged; no prefetch)
    bf16x8 a[4], b[4];
#pragma unroll
    for (int i = 0; i < 4; ++i) {
      const int ra = wm + i * 16 + l16;
      const int rb = wn + i * 16 + l16;
      a[i] = *(const bf16x8*)&As[cur][ra * 32 + swz(ra, quad) * 8];
      b[i] = *(const bf16x8*)&Bs[cur][rb * 32 + swz(rb, quad) * 8];
    }
#pragma unroll
    for (int mi = 0; mi < 4; ++mi)
#pragma unroll
      for (int ni = 0; ni < 4; ++ni)
        acc[mi][ni] = __builtin_amdgcn_mfma_f32_16x16x32_bf16(a[mi], b[ni], acc[mi][ni], 0, 0, 0);
  }

  // epilogue: C/D layout col=lane&15, row=quad*4+r (verified m89/m91)
#pragma unroll
  for (int ni = 0; ni < 4; ++ni) {
    const int coln = n0 + wn + ni * 16 + l16;
    const float bv = bias[coln];
#pragma unroll
    for (int mi = 0; mi < 4; ++mi) {
#pragma unroll
      for (int r = 0; r < 4; ++r) {
        const int rowm = m0 + wm + mi * 16 + quad * 4 + r;
        C[(size_t)rowm * NQKV + coln] = f2bf(acc[mi][ni][r] + bv);
      }
    }
  }
}

// ---------------------------------------------------------------------------
// Fused sparse attention: ONE WAVE PER NODE; lane l owns dims l*8..l*8+7
// (all inside head l>>3). qkv row (u32 view, stride 768): [0,256)=q pairs,
// [256,768)=packed kv (lo=k, hi=v). Per edge: 2x dwordx4 gather, 8 fma dot,
// 3-shuffle group reduce, 1 exp/lane, 8 fma accumulate. Chunks of 4 for ILP.
// ---------------------------------------------------------------------------
__global__ __launch_bounds__(256) void attn_agg(
    const u16* __restrict__ qkv16, const u32* __restrict__ qkv32,
    const int* __restrict__ row_ptr, const int* __restrict__ dst,
    float* __restrict__ out) {
  const int gt = blockIdx.x * 256 + threadIdx.x;
  const int node = gt >> 6;
  const int lane = gt & 63;
  const u16x8 qr = *(const u16x8*)&qkv16[(size_t)node * NQKV + lane * 8];
  float qf[8];
#pragma unroll
  for (int j = 0; j < 8; ++j) qf[j] = bf2f(qr[j]);

  const int beg = row_ptr[node];
  const int end = row_ptr[node + 1];
  float acc[8] = {0.f,0.f,0.f,0.f,0.f,0.f,0.f,0.f};
  float denom = 0.f;

  for (int e = beg; e < end; e += 4) {
    u32 p[4][8];
    int idx[4];
#pragma unroll
    for (int jj = 0; jj < 4; ++jj) {
      const int ee = min(e + jj, end - 1);
      idx[jj] = dst[ee];
    }
#pragma unroll
    for (int jj = 0; jj < 4; ++jj) {
      const u32* pp = qkv32 + (size_t)idx[jj] * 768 + 256 + lane * 8;
      *(u32x4*)&p[jj][0] = *(const u32x4*)pp;        // dwordx4
      *(u32x4*)&p[jj][4] = *(const u32x4*)(pp + 4);  // dwordx4
    }
#pragma unroll
    for (int jj = 0; jj < 4; ++jj) {
      float s = 0.f;
#pragma unroll
      for (int j = 0; j < 8; ++j) s = fmaf(qf[j], bflo(p[jj][j]), s);
      s += __shfl_xor(s, 1, 64);   // reduce within the 8-lane head group
      s += __shfl_xor(s, 2, 64);
      s += __shfl_xor(s, 4, 64);
      const float ex = (e + jj < end) ? __expf(s) : 0.f;
      denom += ex;
#pragma unroll
      for (int j = 0; j < 8; ++j) acc[j] = fmaf(ex, bfhi(p[jj][j]), acc[j]);
    }
  }

  const float inv = (end > beg) ? (1.0f / denom) : 0.f;   // deg-0 rows -> 0
  float4 o0 = { acc[0] * inv, acc[1] * inv, acc[2] * inv, acc[3] * inv };
  float4 o1 = { acc[4] * inv, acc[5] * inv, acc[6] * inv, acc[7] * inv };
  float* op = &out[(size_t)node * 512 + lane * 8];
  *(float4*)op = o0;
  *(float4*)(op + 4) = o1;
}

// ---------------------------------------------------------------------------
extern "C" void kernel_launch(void* const* d_in, const int* in_sizes, int n_in,
                              void* d_out, int out_size, void* d_ws, size_t ws_size,
                              hipStream_t stream) {
  const float* h   = (const float*)d_in[0];
  const int*   row = (const int*)d_in[1];
  const int*   col = (const int*)d_in[2];
  const float* Win = (const float*)d_in[3];
  const float* bin = (const float*)d_in[4];
  const float* Wq  = (const float*)d_in[5];
  const float* bq  = (const float*)d_in[6];
  const float* Wk  = (const float*)d_in[7];
  const float* bk  = (const float*)d_in[8];
  const float* Wv  = (const float*)d_in[9];
  const float* bv  = (const float*)d_in[10];
  float* out = (float*)d_out;

  char* ws = (char*)d_ws;
  u16*   qkv     = (u16*)(ws + 0);           // 32768*1536*2 = 100,663,296
  u16*   hb      = (u16*)(ws + 100663296);   // 32768*512*2  =  33,554,432
  u16*   Wt      = (u16*)(ws + 134217728);   // 1536*512*2   =   1,572,864
  float* bias    = (float*)(ws + 135790592); // 1536*4
  int*   deg     = (int*)(ws + 135796736);   // 32768*4
  int*   row_ptr = (int*)(ws + 135927808);   // 32769*4 (+pad)
  int*   cursor  = (int*)(ws + 136058888);   // 32768*4
  int*   dst     = (int*)(ws + 136189960);   // 262144*4
  // transient (aliased into qkv region; consumed by gemm_wt BEFORE gemm_qkv
  // writes qkv — same-stream ordering makes this safe):
  u16*   At      = (u16*)(ws + 0);           // 1536*512*2 = 1,572,864
  u16*   Winb    = (u16*)(ws + 1572864);     //  512*512*2 =   524,288

  (void)hipMemsetAsync(deg, 0, NN * sizeof(int), stream);
  hipLaunchKernelGGL(tcast_w,   dim3(8, 8, 3), dim3(256), 0, stream, Wq, Wk, Wv, At);
  hipLaunchKernelGGL(cast_win,  dim3((512 * 512 / 8) / 256), dim3(256), 0, stream, Win, Winb);
  hipLaunchKernelGGL(make_bias, dim3(6), dim3(256), 0, stream, bin, Wq, bq, Wk, bk, Wv, bv, bias);
  hipLaunchKernelGGL(cast_h,    dim3((NN * DM / 8) / 256), dim3(256), 0, stream, h, hb);
  hipLaunchKernelGGL(count_deg, dim3(EE / 256), dim3(256), 0, stream, row, deg);
  hipLaunchKernelGGL(scan_deg,  dim3(1), dim3(1024), 0, stream, deg, row_ptr, cursor);
  hipLaunchKernelGGL(fill_csr,  dim3(EE / 256), dim3(256), 0, stream, row, col, cursor, dst);
  hipLaunchKernelGGL(gemm_wt,   dim3(512 / 128, 1536 / 128), dim3(256), 0, stream, At, Winb, Wt);
  hipLaunchKernelGGL(gemm_qkv,  dim3(NQKV / 128, NN / 128), dim3(256), 0, stream, hb, Wt, bias, qkv);
  hipLaunchKernelGGL(attn_agg,  dim3((NN * 64) / 256), dim3(256), 0, stream,
                     qkv, (const u32*)qkv, row_ptr, dst, out);
}